// Round 13
// baseline (439.673 us; speedup 1.0000x reference)
//
#include <hip/hip_runtime.h>

typedef float f32x16 __attribute__((ext_vector_type(16)));
typedef int   i32x8  __attribute__((ext_vector_type(8)));
typedef int   i32x4  __attribute__((ext_vector_type(4)));
typedef unsigned char uchar;

#define KEPS 1e-8f
#define BM 128
#define BN 128
#define BK 64    // one K=64 scaled-MFMA step per kt; 16 K-iterations

// ---------------- 1) row L2-normalize: fp32 norms + fp8 e4m3 copy -----------
__global__ __launch_bounds__(256) void k_normalize(
    const float* __restrict__ in, uchar* __restrict__ xq,
    float* __restrict__ norms, unsigned long long* __restrict__ best,
    float* __restrict__ psum, int D)
{
    const int row = blockIdx.x;
    const int t = threadIdx.x;
    const float4* inr = (const float4*)(in + (size_t)row * D);
    float4 v = inr[t];                       // D=1024 -> 256 float4
    float ss = v.x*v.x + v.y*v.y + v.z*v.z + v.w*v.w;
    for (int off = 32; off; off >>= 1) ss += __shfl_down(ss, off);
    __shared__ float red[4];
    const int lane = t & 63, wave = t >> 6;
    if (lane == 0) red[wave] = ss;
    __syncthreads();
    const float total = red[0] + red[1] + red[2] + red[3];
    const float nrm = sqrtf(total);
    const float inv = 1.0f / fmaxf(nrm, KEPS);
    unsigned r = 0;
    r = __builtin_amdgcn_cvt_pk_fp8_f32(v.x * inv, v.y * inv, r, 0);
    r = __builtin_amdgcn_cvt_pk_fp8_f32(v.z * inv, v.w * inv, r, 1);
    ((unsigned*)(xq + (size_t)row * D))[t] = r;
    if (t == 0) {
        norms[row] = nrm;
        best[row] = 0ull;                    // any real packed key beats 0
    }
    if (row < 256 && t == 1) psum[row * 16] = 0.0f;   // cache-line-padded partials
}

__device__ __forceinline__ unsigned long long pack_key(float v, unsigned idx)
{
    unsigned ub = __float_as_uint(v);
    ub = (ub & 0x80000000u) ? ~ub : (ub | 0x80000000u); // monotonic map
    return ((unsigned long long)ub << 32) | (unsigned long long)(~idx);
}

// ---------------- 2) x x^T triangular MX-fp8 GEMM, dbuf LDS -----------------
// MX layouts verified (R10-R12, absmax 0.0). R12's residual: 39% VALUBusy
// from per-kt pointer bumps + LDS addr recompute + fragment-assembly movs.
// R13: near-zero-VALU K-loop —
//   * 8 LDS read pointers precomputed (swizzle folded in, loop-invariant)
//   * #pragma unroll 2: buffer select (kt&1)*16384 is compile-time
//   * fragments filled in place (i32x4 halves of the i32x8 operand)
//   * staging: uniform SGPR base xq+(kt+1)*64 + 32-bit lane offsets (saddr)
// Inner: mfma_scale_f32_32x32x64_f8f6f4, unit scales (e8m0=127), 2x fp8 rate.
// Triangular covering bx >= by; row-pass + col-pass (off-diag) covers every
// unordered pair; duplicates harmless under idempotent atomicMax.
__global__ __launch_bounds__(256, 3) void k_gemm_argmax(
    const uchar* __restrict__ xq, unsigned long long* __restrict__ best,
    int T)
{
    // triangular mapping: p -> (by, bx), bx >= by
    const int p = blockIdx.x;
    const float tf = (float)T + 0.5f;
    int by = (int)(tf - sqrtf(tf * tf - 2.0f * (float)p));
    while (by > 0 && p < by * T - by * (by - 1) / 2) --by;
    while (p >= (by + 1) * T - (by + 1) * by / 2) ++by;
    const int bx = by + (p - (by * T - by * (by - 1) / 2));

    __shared__ uchar lds[2][(BM + BN) * BK];   // 2 x 16 KiB contiguous
    const int t    = threadIdx.x;
    const int lane = t & 63;
    const int wave = t >> 6;
    const int m    = lane & 31;
    const int half = lane >> 5;
    const int wrow = (wave >> 1) * 64;
    const int wcol = (wave & 1) * 64;
    const int m0   = by * BM;
    const int n0   = bx * BN;

    f32x16 acc[2][2] = {};

    // staging: thread t stages 16B chunks; stored col = t&3, global col
    // swizzled so ds_read_b128 lands conflict-light.
    const int row_s = t >> 2;
    const int col_s = t & 3;
    const int gsw = (col_s ^ ((row_s ^ (row_s >> 2)) & 3)) * 16;  // byte col
    // 32-bit per-lane global offsets (relative to xq + kt*BK)
    const int sA0 = (m0 + row_s) * 1024 + gsw;
    const int sA1 = sA0 + 64 * 1024;
    const int sB0 = (n0 + row_s) * 1024 + gsw;
    const int sB1 = sB0 + 64 * 1024;
    const int l16 = t * 16;

    // loop-invariant LDS read pointers (into buffer 0); buffer 1 = +16384
    const uchar* pa[2][2];
    const uchar* pb[2][2];
    #pragma unroll
    for (int i = 0; i < 2; ++i) {
        const int ra = wrow + i * 32 + m;
        const int sa = (ra ^ (ra >> 2)) & 3;
        pa[i][0] = &lds[0][ra * 64 + (((2 * half)     ^ sa) * 16)];
        pa[i][1] = &lds[0][ra * 64 + (((2 * half + 1) ^ sa) * 16)];
        const int rb = wcol + i * 32 + m;
        const int sb = (rb ^ (rb >> 2)) & 3;
        pb[i][0] = &lds[0][8192 + rb * 64 + (((2 * half)     ^ sb) * 16)];
        pb[i][1] = &lds[0][8192 + rb * 64 + (((2 * half + 1) ^ sb) * 16)];
    }

#define GL(gk, go, dofs)                                                             \
    __builtin_amdgcn_global_load_lds(                                                \
        (const __attribute__((address_space(1))) void*)((gk) + (go)),                \
        (__attribute__((address_space(3))) void*)(&lds[0][0] + (dofs) + l16), 16, 0, 0)

    {   // prologue: stage kt=0 into buffer 0
        const uchar* gk = xq;
        GL(gk, sA0, 0); GL(gk, sA1, 4096); GL(gk, sB0, 8192); GL(gk, sB1, 12288);
    }
    __syncthreads();

    const unsigned sc1 = 0x7F7F7F7Fu;    // e8m0 = 127 -> scale 2^0 = 1.0

    #pragma unroll 2
    for (int kt = 0; kt < 16; ++kt) {
        const int bsel = (kt & 1) * 16384;          // compile-time under unroll 2
        if (kt < 15) {
            const uchar* gk = xq + (kt + 1) * BK;   // uniform SGPR base
            const int dsel = bsel ^ 16384;
            GL(gk, sA0, dsel); GL(gk, sA1, dsel + 4096);
            GL(gk, sB0, dsel + 8192); GL(gk, sB1, dsel + 12288);
        }
        i32x8 a[2], b[2];
        #pragma unroll
        for (int i = 0; i < 2; ++i) {
            ((i32x4*)&a[i])[0] = *(const i32x4*)(pa[i][0] + bsel);
            ((i32x4*)&a[i])[1] = *(const i32x4*)(pa[i][1] + bsel);
        }
        #pragma unroll
        for (int j = 0; j < 2; ++j) {
            ((i32x4*)&b[j])[0] = *(const i32x4*)(pb[j][0] + bsel);
            ((i32x4*)&b[j])[1] = *(const i32x4*)(pb[j][1] + bsel);
        }
        #pragma unroll
        for (int i = 0; i < 2; ++i)
            #pragma unroll
            for (int j = 0; j < 2; ++j)
                acc[i][j] = __builtin_amdgcn_mfma_scale_f32_32x32x64_f8f6f4(
                    a[i], b[j], acc[i][j], 0 /*cbsz: fp8*/, 0 /*blgp: fp8*/,
                    0, sc1, 0, sc1);
        __syncthreads();
    }
#undef GL

    // ---- row-wise argmax (this wave's 64 rows, over its 64 cols) ----
    // C/D: col = lane&31, row = (reg&3) + 8*(reg>>2) + 4*half.
    #pragma unroll
    for (int i = 0; i < 2; ++i) {
        #pragma unroll
        for (int reg = 0; reg < 16; ++reg) {
            const int grow = m0 + wrow + i * 32 + (reg & 3) + 8 * (reg >> 2) + 4 * half;
            float v = -3.0f; unsigned c = 0xFFFFFFFFu;
            #pragma unroll
            for (int j = 0; j < 2; ++j) {
                const int col = n0 + wcol + j * 32 + m;
                const float val = acc[i][j][reg];
                if (col != grow && (val > v || (val == v && (unsigned)col < c))) {
                    v = val; c = (unsigned)col;
                }
            }
            // reduce across the 32 lanes of this half (xor<32 keeps half)
            for (int off = 16; off; off >>= 1) {
                const float    ov = __shfl_xor(v, off);
                const unsigned oc = (unsigned)__shfl_xor((int)c, off);
                if (ov > v || (ov == v && oc < c)) { v = ov; c = oc; }
            }
            if (m == 0) atomicMax(best + grow, pack_key(v, c));
        }
    }

    // ---- col-wise argmax (off-diagonal blocks only) ----
    if (bx != by) {
        #pragma unroll
        for (int j = 0; j < 2; ++j) {
            const int gcol = n0 + wcol + j * 32 + m;
            float v = -3.0f; unsigned c = 0xFFFFFFFFu;
            #pragma unroll
            for (int i = 0; i < 2; ++i) {
                #pragma unroll
                for (int reg = 0; reg < 16; ++reg) {
                    const int grow = m0 + wrow + i * 32 + (reg & 3) + 8 * (reg >> 2) + 4 * half;
                    const float val = acc[i][j][reg];
                    if (val > v || (val == v && (unsigned)grow < c)) {
                        v = val; c = (unsigned)grow;
                    }
                }
            }
            // combine the two halves holding the same col
            {
                const float    ov = __shfl_xor(v, 32);
                const unsigned oc = (unsigned)__shfl_xor((int)c, 32);
                if (ov > v || (ov == v && oc < c)) { v = ov; c = oc; }
            }
            if (half == 0) atomicMax(best + gcol, pack_key(v, c));
        }
    }
}

// ---------------- 3) pairwise distance + log -> 256 padded partials ---------
__global__ __launch_bounds__(256) void k_dist(
    const float* __restrict__ in, const float* __restrict__ norms,
    const unsigned long long* __restrict__ best, float* __restrict__ psum, int D)
{
    const int row = blockIdx.x;
    const int t = threadIdx.x;
    const unsigned long long key = best[row];
    const int nb = (int)(~(unsigned)key);        // recover neighbor index
    const float invi = 1.0f / fmaxf(norms[row], KEPS);
    const float invj = 1.0f / fmaxf(norms[nb], KEPS);
    const float4* xi = (const float4*)(in + (size_t)row * D);
    const float4* xj = (const float4*)(in + (size_t)nb * D);
    const float4 a = xi[t], b = xj[t];
    const float dx = a.x * invi - b.x * invj + KEPS;
    const float dy = a.y * invi - b.y * invj + KEPS;
    const float dz = a.z * invi - b.z * invj + KEPS;
    const float dw = a.w * invi - b.w * invj + KEPS;
    float ss = dx*dx + dy*dy + dz*dz + dw*dw;
    for (int off = 32; off; off >>= 1) ss += __shfl_down(ss, off);
    __shared__ float red[4];
    const int lane = t & 63, wave = t >> 6;
    if (lane == 0) red[wave] = ss;
    __syncthreads();
    if (t == 0) {
        const float tot = red[0] + red[1] + red[2] + red[3];
        // scatter over 256 cache-line-padded slots: 64 atomics/slot, no hotspot
        atomicAdd(psum + (row & 255) * 16, logf(sqrtf(tot) + KEPS));
    }
}

// ---------------- 4) finalize: reduce 256 partials --------------------------
__global__ void k_final(const float* __restrict__ psum, float* __restrict__ out, float invN)
{
    const int t = threadIdx.x;                   // 64 threads
    float s = psum[t * 16] + psum[(t + 64) * 16]
            + psum[(t + 128) * 16] + psum[(t + 192) * 16];
    for (int off = 32; off; off >>= 1) s += __shfl_down(s, off);
    if (t == 0) out[0] = -s * invN;
}

extern "C" void kernel_launch(void* const* d_in, const int* in_sizes, int n_in,
                              void* d_out, int out_size, void* d_ws, size_t ws_size,
                              hipStream_t stream)
{
    const float* in = (const float*)d_in[0];
    const int D = 1024;
    const int N = in_sizes[0] / D;               // 16384

    char* ws = (char*)d_ws;
    uchar* xq = (uchar*)ws;                                      // N*D = 16 MiB
    size_t off = (size_t)N * D;
    float* norms = (float*)(ws + off);           off += (size_t)N * 4;
    unsigned long long* best = (unsigned long long*)(ws + off); off += (size_t)N * 8;
    float* psum = (float*)(ws + off);            // 256 slots x 16 floats
    float* out = (float*)d_out;

    k_normalize<<<N, 256, 0, stream>>>(in, xq, norms, best, psum, D);
    const int T = N / BM;                        // 128 tiles per dim
    const int P = T * (T + 1) / 2;               // 8256 upper-tri blocks
    k_gemm_argmax<<<P, 256, 0, stream>>>(xq, best, T);
    k_dist<<<N, 256, 0, stream>>>(in, norms, best, psum, D);
    k_final<<<1, 64, 0, stream>>>(psum, out, 1.0f / (float)N);
}